// Round 3
// baseline (200.388 us; speedup 1.0000x reference)
//
#include <hip/hip_runtime.h>
#include <hip/hip_bf16.h>
#include <math.h>

#define NB 4
#define LQ 768
#define NH 8
#define NE 64
#define ND 192   // 3*E augmented feature dim
#define TEMP 0.125f

typedef __attribute__((ext_vector_type(8))) __bf16 bf16x8;
typedef __attribute__((ext_vector_type(4))) float f32x4;

// ---------------- prep: augmented double-bf16 (hi/lo) Q' and K' ----------------
// Fast-path transcendentals with exact phase range-reduction:
// phase_k = 2*pi*f*l, f = sigmoid(freqs)/2. Split f = fh + fl (12-bit hi) so
// l*fh is exact in fp32; frac via floor; correct with fma(l, fl). Then
// __sinf/__cosf see args in [-6, 13] where they are ~2 ulp.
__global__ __launch_bounds__(256) void sinattn_prep(
    const float* __restrict__ Q, const float* __restrict__ K,
    const float* __restrict__ freqs, const float* __restrict__ offsets,
    const float* __restrict__ gains, const float* __restrict__ gate,
    __hip_bfloat16* __restrict__ Qhi, __hip_bfloat16* __restrict__ Qlo,
    __hip_bfloat16* __restrict__ Khi, __hip_bfloat16* __restrict__ Klo)
{
    int idx = blockIdx.x * 256 + threadIdx.x;       // ((n*L + l)*H + h)*E + e
    if (idx >= NB * LQ * NH * NE) return;
    int e = idx & 63;
    int h = (idx >> 6) & 7;
    int t = idx >> 9;
    int l = t % LQ;
    int n = t / LQ;
    int he = (h << 6) | e;

    float fr = freqs[he];
    float f  = 0.5f / (1.0f + __expf(-fr));          // sigmoid(fr)/2
    float off = offsets[he];
    float gn  = gains[he];
    float g   = (gn > 15.0f) ? gn : __logf(1.0f + __expf(gn)); // softplus
    float gt  = gate[he];
    float a   = (1.0f - gt) * g * g;

    // exact-ish frac(l*f) in revolutions
    float fh = __uint_as_float(__float_as_uint(f) & 0xFFFFF000u);
    float fl = f - fh;
    float lf = (float)l;
    float t0 = lf * fh;                  // exact (<=23 mantissa bits)
    float tr = t0 - floorf(t0);          // exact frac
    tr = __builtin_fmaf(lf, fl, tr);     // [0, ~1.1) revolutions
    float pk = 6.28318530717958647f * tr;
    float pq = pk + off;
    float sq = __sinf(pq), cq = __cosf(pq);
    float sk = __sinf(pk), ck = __cosf(pk);

    float q = Q[idx], k = K[idx];
    int nh = (n << 3) | h;
    int base = (nh * LQ + l) * ND;

    float qv[3] = { q * a * cq, q * a * sq, q * gt };
    float kv[3] = { k * ck,     k * sk,     k      };
    #pragma unroll
    for (int p = 0; p < 3; ++p) {
        __hip_bfloat16 qh = __float2bfloat16(qv[p]);
        __hip_bfloat16 kh = __float2bfloat16(kv[p]);
        Qhi[base + p * NE + e] = qh;
        Qlo[base + p * NE + e] = __float2bfloat16(qv[p] - __bfloat162float(qh));
        Khi[base + p * NE + e] = kh;
        Klo[base + p * NE + e] = __float2bfloat16(kv[p] - __bfloat162float(kh));
    }
}

// ---------------- V transpose: [n][s][h][e] fp32 -> Vt[nh][e][s] bf16 ----------------
// grid 384 (nh x 12 s-tiles), 256 threads.
__global__ __launch_bounds__(256) void sinattn_vt(
    const float* __restrict__ V, __hip_bfloat16* __restrict__ Vt)
{
    __shared__ __hip_bfloat16 tile[64][72];   // [e][s_local], row = 144B (16B-mult)
    int b = blockIdx.x;
    int st = b % 12, nh = b / 12;
    int n = nh >> 3, h = nh & 7;
    int s0 = st * 64;
    int tid = threadIdx.x;

    int sl = tid >> 2, e0 = (tid & 3) << 4;
    const float4* vp = (const float4*)(V + ((size_t)((n * LQ + s0 + sl) * NH) + h) * NE + e0);
    float4 a0 = vp[0], a1 = vp[1], a2 = vp[2], a3 = vp[3];
    float vv[16] = { a0.x,a0.y,a0.z,a0.w, a1.x,a1.y,a1.z,a1.w,
                     a2.x,a2.y,a2.z,a2.w, a3.x,a3.y,a3.z,a3.w };
    #pragma unroll
    for (int j = 0; j < 16; ++j) tile[e0 + j][sl] = __float2bfloat16(vv[j]);
    __syncthreads();

    int er = tid >> 2, sc = tid & 3;
    __hip_bfloat16* op = Vt + ((size_t)nh * NE + er) * LQ + s0 + sc * 16;
    *(uint4*)op       = *(const uint4*)&tile[er][sc * 16];
    *(uint4*)(op + 8) = *(const uint4*)&tile[er][sc * 16 + 8];
}

// ---------------- flash attention, double-bf16 QK^T, bf16 PV ----------------
// grid 384: nh = bid&31 (XCD swizzle: same nh -> same XCD), lt = bid>>5.
// Software pipeline: K chunk c+1 prefetched into registers during chunk c.
__global__ __launch_bounds__(256, 2) void sinattn_flash(
    const __hip_bfloat16* __restrict__ Qhi, const __hip_bfloat16* __restrict__ Qlo,
    const __hip_bfloat16* __restrict__ Khi, const __hip_bfloat16* __restrict__ Klo,
    const __hip_bfloat16* __restrict__ Vt, const float* __restrict__ mask,
    const float* __restrict__ keylen, float* __restrict__ out)
{
    __shared__ __attribute__((aligned(16))) __hip_bfloat16 sKhi[64 * 200];
    __shared__ __attribute__((aligned(16))) __hip_bfloat16 sKlo[64 * 200];
    __shared__ __attribute__((aligned(16))) __hip_bfloat16 sP[4][16 * 72];

    int tid  = threadIdx.x;
    int wv   = tid >> 6;
    int lane = tid & 63;
    int grp  = lane >> 4;
    int r16  = lane & 15;

    int bid = blockIdx.x;
    int nh  = bid & 31;
    int lt  = bid >> 5;
    int n   = nh >> 3;
    int l0  = lt * 64;

    // Q fragments (A-layout) straight from global, reused across all chunks.
    bf16x8 qhi[6], qlo[6];
    {
        size_t rbase = (size_t)(nh * LQ + l0 + wv * 16 + r16) * ND + grp * 8;
        #pragma unroll
        for (int d0 = 0; d0 < 6; ++d0) {
            qhi[d0] = *(const bf16x8*)(Qhi + rbase + d0 * 32);
            qlo[d0] = *(const bf16x8*)(Qlo + rbase + d0 * 32);
        }
    }

    // staging thread mapping: 1536 chunks of 8 bf16, 6 per thread
    int goff[6], ldso[6];
    #pragma unroll
    for (int i = 0; i < 6; ++i) {
        int cj  = tid + 256 * i;
        int row = cj / 24;
        int cc  = cj - row * 24;
        goff[i] = row * ND + cc * 8;
        ldso[i] = row * 200 + cc * 8;
    }
    const __hip_bfloat16* Kh0 = Khi + (size_t)nh * LQ * ND;
    const __hip_bfloat16* Kl0 = Klo + (size_t)nh * LQ * ND;

    // prefetch chunk 0
    uint4 kh[6], kl[6];
    #pragma unroll
    for (int i = 0; i < 6; ++i) {
        kh[i] = *(const uint4*)(Kh0 + goff[i]);
        kl[i] = *(const uint4*)(Kl0 + goff[i]);
    }

    float m_i[4], l_i[4];
    f32x4 O[4];
    #pragma unroll
    for (int rr = 0; rr < 4; ++rr) { m_i[rr] = -INFINITY; l_i[rr] = 0.f; }
    #pragma unroll
    for (int tt = 0; tt < 4; ++tt)
        #pragma unroll
        for (int rr = 0; rr < 4; ++rr) O[tt][rr] = 0.f;

    for (int c = 0; c < 12; ++c) {
        int s0 = c * 64;
        __syncthreads();   // prior chunk's sK readers done
        #pragma unroll
        for (int i = 0; i < 6; ++i) {
            *(uint4*)&sKhi[ldso[i]] = kh[i];
            *(uint4*)&sKlo[ldso[i]] = kl[i];
        }
        __syncthreads();   // staging visible

        // prefetch next K chunk into registers (in flight during compute)
        if (c < 11) {
            const __hip_bfloat16* ah = Kh0 + (s0 + 64) * ND;
            const __hip_bfloat16* al = Kl0 + (s0 + 64) * ND;
            #pragma unroll
            for (int i = 0; i < 6; ++i) {
                kh[i] = *(const uint4*)(ah + goff[i]);
                kl[i] = *(const uint4*)(al + goff[i]);
            }
        }

        // V fragments direct from global (bf16, transposed layout)
        bf16x8 vf[2][4];
        #pragma unroll
        for (int kk = 0; kk < 2; ++kk)
            #pragma unroll
            for (int tt = 0; tt < 4; ++tt)
                vf[kk][tt] = *(const bf16x8*)(Vt + ((size_t)nh * NE + tt * 16 + r16) * LQ
                                              + s0 + kk * 32 + grp * 8);
        // mask / keylen prefetch
        float mreg[4][4], klv[4];
        #pragma unroll
        for (int j = 0; j < 4; ++j) klv[j] = keylen[n * LQ + s0 + j * 16 + r16];
        #pragma unroll
        for (int rr = 0; rr < 4; ++rr) {
            int lrow = l0 + wv * 16 + grp * 4 + rr;
            #pragma unroll
            for (int j = 0; j < 4; ++j)
                mreg[rr][j] = mask[lrow * LQ + s0 + j * 16 + r16];
        }

        // S = Q'.K'^T double-bf16: hi*hi + lo*hi + hi*lo
        f32x4 st[4];
        #pragma unroll
        for (int j = 0; j < 4; ++j)
            #pragma unroll
            for (int rr = 0; rr < 4; ++rr) st[j][rr] = 0.f;
        #pragma unroll
        for (int d0 = 0; d0 < 6; ++d0) {
            #pragma unroll
            for (int j = 0; j < 4; ++j) {
                bf16x8 bhi = *(const bf16x8*)&sKhi[(j * 16 + r16) * 200 + d0 * 32 + grp * 8];
                bf16x8 blo = *(const bf16x8*)&sKlo[(j * 16 + r16) * 200 + d0 * 32 + grp * 8];
                st[j] = __builtin_amdgcn_mfma_f32_16x16x32_bf16(qhi[d0], bhi, st[j], 0, 0, 0);
                st[j] = __builtin_amdgcn_mfma_f32_16x16x32_bf16(qlo[d0], bhi, st[j], 0, 0, 0);
                st[j] = __builtin_amdgcn_mfma_f32_16x16x32_bf16(qhi[d0], blo, st[j], 0, 0, 0);
            }
        }

        // online softmax (C layout: col=r16 (+16j), row=grp*4+rr)
        #pragma unroll
        for (int rr = 0; rr < 4; ++rr) {
            float lg[4];
            float mx = -INFINITY;
            #pragma unroll
            for (int j = 0; j < 4; ++j) {
                lg[j] = TEMP * (st[j][rr] + mreg[rr][j] + klv[j]);
                mx = fmaxf(mx, lg[j]);
            }
            #pragma unroll
            for (int d = 1; d < 16; d <<= 1) mx = fmaxf(mx, __shfl_xor(mx, d));
            float mnew  = fmaxf(m_i[rr], mx);
            float alpha = __expf(m_i[rr] - mnew);
            float rs = 0.f;
            #pragma unroll
            for (int j = 0; j < 4; ++j) {
                float p = __expf(lg[j] - mnew);
                rs += p;
                sP[wv][(grp * 4 + rr) * 72 + j * 16 + r16] = __float2bfloat16(p);
            }
            #pragma unroll
            for (int d = 1; d < 16; d <<= 1) rs += __shfl_xor(rs, d);
            l_i[rr] = l_i[rr] * alpha + rs;
            m_i[rr] = mnew;
            #pragma unroll
            for (int tt = 0; tt < 4; ++tt) O[tt][rr] *= alpha;
        }
        // no barrier: sP round-trip is strictly per-wave (in-order LDS pipe)

        // O += P.V
        #pragma unroll
        for (int kk = 0; kk < 2; ++kk) {
            bf16x8 pa = *(const bf16x8*)&sP[wv][r16 * 72 + kk * 32 + grp * 8];
            #pragma unroll
            for (int tt = 0; tt < 4; ++tt)
                O[tt] = __builtin_amdgcn_mfma_f32_16x16x32_bf16(pa, vf[kk][tt], O[tt], 0, 0, 0);
        }
    }

    // epilogue
    #pragma unroll
    for (int rr = 0; rr < 4; ++rr) {
        float inv = 1.0f / l_i[rr];
        int lrow = l0 + wv * 16 + grp * 4 + rr;
        float* op = out + ((size_t)(n * LQ + lrow) * NH + (nh & 7)) * NE;
        #pragma unroll
        for (int tt = 0; tt < 4; ++tt)
            op[tt * 16 + r16] = O[tt][rr] * inv;
    }
}

extern "C" void kernel_launch(void* const* d_in, const int* in_sizes, int n_in,
                              void* d_out, int out_size, void* d_ws, size_t ws_size,
                              hipStream_t stream)
{
    const float* Q      = (const float*)d_in[0];
    const float* K      = (const float*)d_in[1];
    const float* V      = (const float*)d_in[2];
    const float* mask   = (const float*)d_in[3];
    const float* keylen = (const float*)d_in[4];
    const float* freqs  = (const float*)d_in[5];
    const float* offs   = (const float*)d_in[6];
    const float* gains  = (const float*)d_in[7];
    const float* gate   = (const float*)d_in[8];
    float* out = (float*)d_out;

    const size_t P = (size_t)NB * NH * LQ * ND;   // 4.72M elems / plane
    __hip_bfloat16* Qhi = (__hip_bfloat16*)d_ws;
    __hip_bfloat16* Qlo = Qhi + P;
    __hip_bfloat16* Khi = Qlo + P;
    __hip_bfloat16* Klo = Khi + P;
    __hip_bfloat16* Vt  = Klo + P;                // 32*64*768 bf16 = 3.1 MB

    sinattn_prep<<<6144, 256, 0, stream>>>(Q, K, freqs, offs, gains, gate,
                                           Qhi, Qlo, Khi, Klo);
    sinattn_vt<<<384, 256, 0, stream>>>(V, Vt);
    sinattn_flash<<<NB * NH * (LQ / 64), 256, 0, stream>>>(Qhi, Qlo, Khi, Klo,
                                                           Vt, mask, keylen, out);
}

// Round 4
// 122.326 us; speedup vs baseline: 1.6381x; 1.6381x over previous
//
#include <hip/hip_runtime.h>
#include <math.h>
#include <stdint.h>

#define NB 4
#define LQ 768
#define NH 8
#define NE 64
#define ND 192   // 3*E augmented feature dim
#define TEMP 0.125f

typedef _Float16 f16;
typedef __attribute__((ext_vector_type(8))) _Float16 f16x8;
typedef __attribute__((ext_vector_type(4))) float f32x4;

// Async global->LDS 16B: HW writes lds_base + lane*16. lds_base must be
// wave-uniform; global address is per-lane. Fallback: manual write.
__device__ __forceinline__ void stage16(f16* lds_base, const f16* g, int lane) {
#if __has_builtin(__builtin_amdgcn_global_load_lds)
    __builtin_amdgcn_global_load_lds(
        (const __attribute__((address_space(1))) uint32_t*)g,
        (__attribute__((address_space(3))) uint32_t*)lds_base, 16, 0, 0);
#else
    *(uint4*)((char*)lds_base + lane * 16) = *(const uint4*)g;
#endif
}

// ---------------- prep: augmented f16 Q' and K', 8 elems/thread ----------------
__global__ __launch_bounds__(256) void sinattn_prep(
    const float* __restrict__ Q, const float* __restrict__ K,
    const float* __restrict__ freqs, const float* __restrict__ offsets,
    const float* __restrict__ gains, const float* __restrict__ gate,
    f16* __restrict__ Qf, f16* __restrict__ Kf)
{
    int idx = blockIdx.x * 256 + threadIdx.x;   // ((n*L+l)*8 + h)*8 + eg
    int eg = idx & 7, e0 = eg << 3;
    int h  = (idx >> 3) & 7;
    int t  = idx >> 6;                          // n*L + l
    int l  = t % LQ;
    int n  = t / LQ;
    int nh = (n << 3) | h;
    int he = (h << 6) | e0;

    const float* qp = Q + (size_t)idx * 8;      // == ((t*8+h)*64 + e0)
    const float* kp = K + (size_t)idx * 8;
    float4 q0 = *(const float4*)qp, q1 = *(const float4*)(qp + 4);
    float4 k0 = *(const float4*)kp, k1 = *(const float4*)(kp + 4);
    float qv[8] = {q0.x,q0.y,q0.z,q0.w, q1.x,q1.y,q1.z,q1.w};
    float kv[8] = {k0.x,k0.y,k0.z,k0.w, k1.x,k1.y,k1.z,k1.w};

    float4 fA = *(const float4*)(freqs   + he), fB = *(const float4*)(freqs   + he + 4);
    float4 oA = *(const float4*)(offsets + he), oB = *(const float4*)(offsets + he + 4);
    float4 gA = *(const float4*)(gains   + he), gB = *(const float4*)(gains   + he + 4);
    float4 tA = *(const float4*)(gate    + he), tB = *(const float4*)(gate    + he + 4);
    float fv[8] = {fA.x,fA.y,fA.z,fA.w, fB.x,fB.y,fB.z,fB.w};
    float ov[8] = {oA.x,oA.y,oA.z,oA.w, oB.x,oB.y,oB.z,oB.w};
    float gv[8] = {gA.x,gA.y,gA.z,gA.w, gB.x,gB.y,gB.z,gB.w};
    float tv[8] = {tA.x,tA.y,tA.z,tA.w, tB.x,tB.y,tB.z,tB.w};

    f16x8 oq0, oq1, oq2, ok0, ok1, ok2;
    float lf = (float)l;
    #pragma unroll
    for (int j = 0; j < 8; ++j) {
        float f  = 0.5f / (1.0f + __expf(-fv[j]));        // sigmoid/2 (revolutions)
        float gn = gv[j];
        float sp = (gn > 15.0f) ? gn : __logf(1.0f + __expf(gn));
        float gt = tv[j];
        float a  = (1.0f - gt) * sp * sp;
        // exact frac(l*f): split f at 12 mantissa bits
        float fh = __uint_as_float(__float_as_uint(f) & 0xFFFFF000u);
        float fl = f - fh;
        float t0 = lf * fh;
        float tr = t0 - floorf(t0);
        tr = __builtin_fmaf(lf, fl, tr);
        float pk = 6.28318530717958647f * tr;
        float pq = pk + ov[j];
        float sq = __sinf(pq), cq = __cosf(pq);
        float sk = __sinf(pk), ck = __cosf(pk);
        oq0[j] = (f16)(qv[j] * a * cq);
        oq1[j] = (f16)(qv[j] * a * sq);
        oq2[j] = (f16)(qv[j] * gt);
        ok0[j] = (f16)(kv[j] * ck);
        ok1[j] = (f16)(kv[j] * sk);
        ok2[j] = (f16)(kv[j]);
    }
    size_t base = ((size_t)nh * LQ + l) * ND + e0;
    *(f16x8*)(Qf + base)            = oq0;
    *(f16x8*)(Qf + base + NE)       = oq1;
    *(f16x8*)(Qf + base + 2 * NE)   = oq2;
    *(f16x8*)(Kf + base)            = ok0;
    *(f16x8*)(Kf + base + NE)       = ok1;
    *(f16x8*)(Kf + base + 2 * NE)   = ok2;
}

// ---------------- V transpose: [n][s][h][e] fp32 -> Vt[nh][e][s] f16 ----------------
__global__ __launch_bounds__(256) void sinattn_vt(
    const float* __restrict__ V, f16* __restrict__ Vt)
{
    __shared__ f16 tile[64][72];
    int b = blockIdx.x;
    int st = b % 12, nh = b / 12;
    int n = nh >> 3, h = nh & 7;
    int s0 = st * 64;
    int tid = threadIdx.x;

    int sl = tid >> 2, e0 = (tid & 3) << 4;
    const float4* vp = (const float4*)(V + ((size_t)(n * LQ + s0 + sl) * NH + h) * NE + e0);
    float4 a0 = vp[0], a1 = vp[1], a2 = vp[2], a3 = vp[3];
    float vv[16] = { a0.x,a0.y,a0.z,a0.w, a1.x,a1.y,a1.z,a1.w,
                     a2.x,a2.y,a2.z,a2.w, a3.x,a3.y,a3.z,a3.w };
    #pragma unroll
    for (int j = 0; j < 16; ++j) tile[e0 + j][sl] = (f16)vv[j];
    __syncthreads();

    int er = tid >> 2, sc = tid & 3;
    f16* op = Vt + ((size_t)nh * NE + er) * LQ + s0 + sc * 16;
    *(uint4*)op       = *(const uint4*)&tile[er][sc * 16];
    *(uint4*)(op + 8) = *(const uint4*)&tile[er][sc * 16 + 8];
}

// ---------------- flash attention, f16 MFMA, async dbuf staging ----------------
// grid 384: nh = bid&31, lt = bid>>5. block 256 (4 waves, 16 q-rows/wave).
// LDS: K chunks stored as 16B chunks, phys chunk p = r*24 + ((c&~7)|((c&7)^(r&7)))
//      V chunks: p = r*8 + (c ^ (r&7)). XOR swizzle -> uniform bank spread on
//      both the lane-linear async writes and the B-fragment b128 reads.
__global__ __launch_bounds__(256, 2) void sinattn_flash(
    const f16* __restrict__ Qf, const f16* __restrict__ Kf, const f16* __restrict__ Vt,
    const float* __restrict__ mask, const float* __restrict__ keylen,
    float* __restrict__ out)
{
    __shared__ __attribute__((aligned(16))) f16 sK[2][64 * 24 * 8];  // 24 KB each
    __shared__ __attribute__((aligned(16))) f16 sV[2][64 * 8 * 8];   // 8 KB each
    __shared__ __attribute__((aligned(16))) f16 sP[4][16 * 72];

    int tid  = threadIdx.x;
    int wv   = tid >> 6;
    int lane = tid & 63;
    int grp  = lane >> 4;
    int r16  = lane & 15;
    int swz  = r16 & 7;

    int bid = blockIdx.x;
    int nh  = bid & 31;
    int lt  = bid >> 5;
    int n   = nh >> 3;
    int l0  = lt * 64;

    // Q fragments (A-layout) from global, live whole kernel: 24 VGPRs
    f16x8 qf[6];
    {
        size_t rbase = ((size_t)nh * LQ + l0 + wv * 16 + r16) * ND + grp * 8;
        #pragma unroll
        for (int d0 = 0; d0 < 6; ++d0)
            qf[d0] = *(const f16x8*)(Qf + rbase + d0 * 32);
    }

    // per-lane swizzled global offsets for staging
    int goffK[6], goffV[2];
    #pragma unroll
    for (int i = 0; i < 6; ++i) {
        int p = i * 256 + wv * 64 + lane;
        int r = p / 24, c = p - r * 24;
        int cl = (c & ~7) | ((c & 7) ^ (r & 7));
        goffK[i] = r * ND + cl * 8;
    }
    #pragma unroll
    for (int i = 0; i < 2; ++i) {
        int p = i * 256 + wv * 64 + lane;
        int r = p >> 3, c = p & 7;
        goffV[i] = r * LQ + (c ^ (r & 7)) * 8;
    }
    const f16* Kb = Kf + (size_t)nh * LQ * ND;
    const f16* Vb = Vt + (size_t)nh * NE * LQ;

    // issue chunk 0 into buffer 0
    {
        #pragma unroll
        for (int i = 0; i < 6; ++i)
            stage16(&sK[0][(i * 256 + wv * 64) * 8], Kb + goffK[i], lane);
        #pragma unroll
        for (int i = 0; i < 2; ++i)
            stage16(&sV[0][(i * 256 + wv * 64) * 8], Vb + goffV[i], lane);
    }

    float m_i[4], l_i[4];
    f32x4 O[4];
    #pragma unroll
    for (int rr = 0; rr < 4; ++rr) { m_i[rr] = -INFINITY; l_i[rr] = 0.f; }
    #pragma unroll
    for (int tt = 0; tt < 4; ++tt)
        #pragma unroll
        for (int rr = 0; rr < 4; ++rr) O[tt][rr] = 0.f;

    for (int c = 0; c < 12; ++c) {
        int cur = c & 1;
        int s0  = c * 64;
        __syncthreads();   // drains vmcnt: sK/sV[cur] landed; prev compute done

        if (c < 11) {      // prefetch next chunk; in flight during this compute
            const f16* kg = Kb + (s0 + 64) * ND;
            const f16* vg = Vb + (s0 + 64);
            #pragma unroll
            for (int i = 0; i < 6; ++i)
                stage16(&sK[cur ^ 1][(i * 256 + wv * 64) * 8], kg + goffK[i], lane);
            #pragma unroll
            for (int i = 0; i < 2; ++i)
                stage16(&sV[cur ^ 1][(i * 256 + wv * 64) * 8], vg + goffV[i], lane);
        }

        // mask / keylen (zero-valued but semantically required; L2-resident)
        float klv[4], mreg[4][4];
        #pragma unroll
        for (int j = 0; j < 4; ++j) klv[j] = keylen[n * LQ + s0 + j * 16 + r16];
        #pragma unroll
        for (int rr = 0; rr < 4; ++rr) {
            int lrow = l0 + wv * 16 + grp * 4 + rr;
            #pragma unroll
            for (int j = 0; j < 4; ++j)
                mreg[rr][j] = mask[lrow * LQ + s0 + j * 16 + r16];
        }

        // S = Q'.K'^T  (f16 MFMA)
        f32x4 st[4];
        #pragma unroll
        for (int j = 0; j < 4; ++j)
            #pragma unroll
            for (int rr = 0; rr < 4; ++rr) st[j][rr] = 0.f;
        #pragma unroll
        for (int d0 = 0; d0 < 6; ++d0) {
            #pragma unroll
            for (int j = 0; j < 4; ++j) {
                int cc = d0 * 4 + grp;
                int cl = (cc & ~7) | ((cc & 7) ^ swz);
                f16x8 bf = *(const f16x8*)&sK[cur][((j * 16 + r16) * 24 + cl) * 8];
                st[j] = __builtin_amdgcn_mfma_f32_16x16x32_f16(qf[d0], bf, st[j], 0, 0, 0);
            }
        }

        // online softmax (C layout: col=r16+16j, row=grp*4+rr)
        #pragma unroll
        for (int rr = 0; rr < 4; ++rr) {
            float lg[4];
            float mx = -INFINITY;
            #pragma unroll
            for (int j = 0; j < 4; ++j) {
                lg[j] = TEMP * (st[j][rr] + mreg[rr][j] + klv[j]);
                mx = fmaxf(mx, lg[j]);
            }
            #pragma unroll
            for (int d = 1; d < 16; d <<= 1) mx = fmaxf(mx, __shfl_xor(mx, d));
            float mnew  = fmaxf(m_i[rr], mx);
            float alpha = __expf(m_i[rr] - mnew);
            float rs = 0.f;
            #pragma unroll
            for (int j = 0; j < 4; ++j) {
                float p = __expf(lg[j] - mnew);
                rs += p;
                sP[wv][(grp * 4 + rr) * 72 + j * 16 + r16] = (f16)p;
            }
            #pragma unroll
            for (int d = 1; d < 16; d <<= 1) rs += __shfl_xor(rs, d);
            l_i[rr] = l_i[rr] * alpha + rs;
            m_i[rr] = mnew;
            #pragma unroll
            for (int tt = 0; tt < 4; ++tt) O[tt][rr] *= alpha;
        }
        // no barrier: sP round-trip is per-wave; LDS ops in-order per wave

        // O += P.V
        #pragma unroll
        for (int kk = 0; kk < 2; ++kk) {
            f16x8 pa = *(const f16x8*)&sP[wv][r16 * 72 + kk * 32 + grp * 8];
            #pragma unroll
            for (int tt = 0; tt < 4; ++tt) {
                int cc = kk * 4 + grp;
                f16x8 vb = *(const f16x8*)&sV[cur][((tt * 16 + r16) * 8 + (cc ^ swz)) * 8];
                O[tt] = __builtin_amdgcn_mfma_f32_16x16x32_f16(pa, vb, O[tt], 0, 0, 0);
            }
        }
    }

    // epilogue: normalize, write out[n][l][h][e] (fp32)
    #pragma unroll
    for (int rr = 0; rr < 4; ++rr) {
        float inv = 1.0f / l_i[rr];
        int lrow = l0 + wv * 16 + grp * 4 + rr;
        float* op = out + ((size_t)(n * LQ + lrow) * NH + (nh & 7)) * NE;
        #pragma unroll
        for (int tt = 0; tt < 4; ++tt)
            op[tt * 16 + r16] = O[tt][rr] * inv;
    }
}

extern "C" void kernel_launch(void* const* d_in, const int* in_sizes, int n_in,
                              void* d_out, int out_size, void* d_ws, size_t ws_size,
                              hipStream_t stream)
{
    const float* Q      = (const float*)d_in[0];
    const float* K      = (const float*)d_in[1];
    const float* V      = (const float*)d_in[2];
    const float* mask   = (const float*)d_in[3];
    const float* keylen = (const float*)d_in[4];
    const float* freqs  = (const float*)d_in[5];
    const float* offs   = (const float*)d_in[6];
    const float* gains  = (const float*)d_in[7];
    const float* gate   = (const float*)d_in[8];
    float* out = (float*)d_out;

    const size_t P = (size_t)NB * NH * LQ * ND;   // 4.72M elems / plane
    f16* Qf = (f16*)d_ws;
    f16* Kf = Qf + P;
    f16* Vt = Kf + P;                             // 32*64*768 f16 = 3.1 MB

    sinattn_prep<<<768, 256, 0, stream>>>(Q, K, freqs, offs, gains, gate, Qf, Kf);
    sinattn_vt<<<384, 256, 0, stream>>>(V, Vt);
    sinattn_flash<<<NB * NH * (LQ / 64), 256, 0, stream>>>(Qf, Kf, Vt,
                                                           mask, keylen, out);
}